// Round 1
// 907.097 us; speedup vs baseline: 1.2128x; 1.2128x over previous
//
#include <hip/hip_runtime.h>

#define N_NODES 100000
#define N_EDGES 1600000
#define E_TBL   200000
#define D       128
#define NREG    50000
#define P_MP    4
#define L_SUB   2
#define D_META  64
#define SCALE_F 0.08838834764831845f   // 1/sqrt(128)

// two-level counting sort geometry
#define BKT_SHIFT 9
#define BKT_NODES 512
#define NBKT      196                     // ceil(100000/512)
#define CSB       128                     // coarse-sort blocks (1.6M/128 = 12500 edges each)
#define EPB       (N_EDGES / CSB)         // 12500
#define P2N       (NBKT * CSB)            // 25088
#define P2B       (P2N / 256)             // 98

typedef __attribute__((ext_vector_type(8))) short bf16x8;
typedef __attribute__((ext_vector_type(4))) float f32x4;

// ---------------- bf16 helpers ----------------

__device__ __forceinline__ float bf2f_lo(unsigned int u) {
    union { unsigned int i; float f; } v;
    v.i = u << 16;                         // low bf16 -> f32 (high bits discarded by shift)
    return v.f;
}
__device__ __forceinline__ float bf2f_hi(unsigned int u) {
    union { unsigned int i; float f; } v;
    v.i = u & 0xffff0000u;                 // high bf16 -> f32
    return v.f;
}
__device__ __forceinline__ unsigned int f2bf(float f) {
    union { float f; unsigned int i; } v;
    v.f = f;
    return (v.i + 0x7fffu + ((v.i >> 16) & 1u)) >> 16;   // RNE
}

// ---------------- CSR build (batched over p via blockIdx.y) ----------------
// P1: per-block bucket histograms, table [p][bucket][block]

__global__ __launch_bounds__(256) void p1_bhist(const int* __restrict__ edge_index,
                                                int* __restrict__ tbl) {
    __shared__ int h[NBKT];
    int p = blockIdx.y, b = blockIdx.x, t = threadIdx.x;
    const int* dst = edge_index + ((size_t)p * 2 + 1) * N_EDGES;
    if (t < NBKT) h[t] = 0;
    __syncthreads();
    int e0 = b * EPB;
    for (int e = e0 + t; e < e0 + EPB; e += 256)
        atomicAdd(&h[dst[e] >> BKT_SHIFT], 1);
    __syncthreads();
    if (t < NBKT) tbl[(size_t)p * P2N + t * CSB + b] = h[t];
}

// P2: single-kernel exclusive scan of the 25088-entry table, one block per p.
// Values staged in registers (25/thread), block scan of per-thread sums in LDS.

__global__ __launch_bounds__(1024) void p2_scan(const int* __restrict__ tbl,
                                                int* __restrict__ tblx,
                                                int* __restrict__ offs) {
    __shared__ int ts[1024];
    int p = blockIdx.x, t = threadIdx.x;
    const int* tp = tbl + (size_t)p * P2N;
    int* xp = tblx + (size_t)p * P2N;
    int v[25];
    int base = t * 25;
    int sum = 0;
#pragma unroll
    for (int i = 0; i < 25; ++i) {
        int idx = base + i;
        int val = (idx < P2N) ? tp[idx] : 0;
        v[i] = val;
        sum += val;
    }
    ts[t] = sum;
    __syncthreads();
    for (int o = 1; o < 1024; o <<= 1) {
        int u = (t >= o) ? ts[t - o] : 0;
        __syncthreads();
        ts[t] += u;
        __syncthreads();
    }
    int run = ts[t] - sum;                 // exclusive across thread chunks
#pragma unroll
    for (int i = 0; i < 25; ++i) {
        int idx = base + i;
        if (idx < P2N) xp[idx] = run;
        run += v[i];
    }
    if (t == 0) offs[(size_t)p * (N_NODES + 1) + N_NODES] = N_EDGES;
}

// P3: coarse scatter of (src,dst) pairs into bucket-contiguous regions.

__global__ __launch_bounds__(256) void p3_coarse(const int* __restrict__ edge_index,
                                                 const int* __restrict__ tblx,
                                                 uint2* __restrict__ pairs) {
    __shared__ int lcur[NBKT];
    int p = blockIdx.y, b = blockIdx.x, t = threadIdx.x;
    const int* src = edge_index + ((size_t)p * 2 + 0) * N_EDGES;
    const int* dst = edge_index + ((size_t)p * 2 + 1) * N_EDGES;
    const int* txp = tblx + (size_t)p * P2N;
    uint2* pp = pairs + (size_t)p * N_EDGES;
    if (t < NBKT) lcur[t] = txp[t * CSB + b];
    __syncthreads();
    int e0 = b * EPB;
    for (int e = e0 + t; e < e0 + EPB; e += 256) {
        int d = dst[e], s0 = src[e];
        int pos = atomicAdd(&lcur[d >> BKT_SHIFT], 1);
        pp[pos] = make_uint2((unsigned)s0, (unsigned)d);
    }
}

// P4: one block per bucket -> offs + fine scatter of ssrc (cnt derived from offs, not stored).

__global__ __launch_bounds__(256) void p4_fine(const uint2* __restrict__ pairs,
                                               const int* __restrict__ tblx,
                                               int* __restrict__ offs,
                                               int* __restrict__ ssrc) {
    __shared__ int lhist[BKT_NODES];
    __shared__ int lcur[BKT_NODES];
    __shared__ int pr[256];
    int p = blockIdx.y, b = blockIdx.x, t = threadIdx.x;
    const uint2* pp = pairs + (size_t)p * N_EDGES;
    const int* txp = tblx + (size_t)p * P2N;
    int* offp = offs + (size_t)p * (N_NODES + 1);
    int* sp = ssrc + (size_t)p * N_EDGES;
    int nbase = b << BKT_SHIFT;
    int e0 = txp[b * CSB];
    int e1 = (b + 1 < NBKT) ? txp[(b + 1) * CSB] : N_EDGES;
    lhist[t] = 0;
    lhist[t + 256] = 0;
    __syncthreads();
    for (int e = e0 + t; e < e1; e += 256)
        atomicAdd(&lhist[pp[e].y - nbase], 1);
    __syncthreads();
    int c0 = lhist[2 * t], c1 = lhist[2 * t + 1];
    int ps = c0 + c1;
    pr[t] = ps;
    __syncthreads();
    for (int o = 1; o < 256; o <<= 1) {
        int u = (t >= o) ? pr[t - o] : 0;
        __syncthreads();
        pr[t] += u;
        __syncthreads();
    }
    int ex = e0 + pr[t] - ps;
    lcur[2 * t] = ex;
    lcur[2 * t + 1] = ex + c0;
    int n0 = nbase + 2 * t;
    if (n0 < N_NODES)     offp[n0] = ex;
    if (n0 + 1 < N_NODES) offp[n0 + 1] = ex + c0;
    __syncthreads();
    for (int e = e0 + t; e < e1; e += 256) {
        uint2 q = pp[e];
        int pos = atomicAdd(&lcur[q.y - nbase], 1);
        sp[pos] = (int)q.x;
    }
}

// ---------------- gather x0 = bf16(E[eids]) (batched over p) ----------------

__global__ __launch_bounds__(256) void k_gather(const float* __restrict__ Etab,
                                                const int* __restrict__ eids,
                                                unsigned short* __restrict__ x0) {
    int p = blockIdx.y;
    int i = blockIdx.x * 256 + threadIdx.x;    // N_NODES*16 threads per p
    int n = i >> 4, g = i & 15;
    if (n >= N_NODES) return;
    int r = eids[(size_t)p * N_NODES + n];
    const float4* srcp = (const float4*)(Etab + (size_t)r * D + g * 8);
    float4 a = srcp[0], b = srcp[1];
    uint4 o;
    o.x = f2bf(a.x) | (f2bf(a.y) << 16);
    o.y = f2bf(a.z) | (f2bf(a.w) << 16);
    o.z = f2bf(b.x) | (f2bf(b.y) << 16);
    o.w = f2bf(b.z) | (f2bf(b.w) << 16);
    *(uint4*)(x0 + ((size_t)p * N_NODES + n) * D + g * 8) = o;
}

// ---------------- SpMM: mean over in-edges, scalar (SGPR) row indices ----------------
// Row index per edge is wave-uniform: fetch edge ids coalesced, broadcast via
// v_readlane into SGPRs so row loads become saddr + lane*4 (no VGPR addr math,
// no ds_bpermute).

__global__ __launch_bounds__(256) void k_spmm(const unsigned short* __restrict__ x,
                                              const int* __restrict__ offs,
                                              const int* __restrict__ ssrc,
                                              unsigned short* __restrict__ sout, int rows) {
    int p = blockIdx.y;
    int lane = threadIdx.x & 63;
    int wv = __builtin_amdgcn_readfirstlane((blockIdx.x * 256 + (int)threadIdx.x) >> 6);
    if (wv >= rows) return;
    const int* offp = offs + (size_t)p * (N_NODES + 1);
    const int* ep = ssrc + (size_t)p * N_EDGES;
    const unsigned int* xb = (const unsigned int*)x + (size_t)p * N_NODES * 64;
    int e0 = __builtin_amdgcn_readfirstlane(offp[wv]);
    int e1 = __builtin_amdgcn_readfirstlane(offp[wv + 1]);
    float ax = 0.f, ay = 0.f;

    int e = e0;
    while (e < e1) {
        int m = min(64, e1 - e);
        int idx = (lane < m) ? ep[e + lane] : 0;       // one coalesced index load
        int j = 0;
        for (; j + 8 <= m; j += 8) {
            int s0 = __builtin_amdgcn_readlane(idx, j + 0);
            int s1 = __builtin_amdgcn_readlane(idx, j + 1);
            int s2 = __builtin_amdgcn_readlane(idx, j + 2);
            int s3 = __builtin_amdgcn_readlane(idx, j + 3);
            int s4 = __builtin_amdgcn_readlane(idx, j + 4);
            int s5 = __builtin_amdgcn_readlane(idx, j + 5);
            int s6 = __builtin_amdgcn_readlane(idx, j + 6);
            int s7 = __builtin_amdgcn_readlane(idx, j + 7);
            unsigned int v0 = xb[(size_t)s0 * 64 + lane];
            unsigned int v1 = xb[(size_t)s1 * 64 + lane];
            unsigned int v2 = xb[(size_t)s2 * 64 + lane];
            unsigned int v3 = xb[(size_t)s3 * 64 + lane];
            unsigned int v4 = xb[(size_t)s4 * 64 + lane];
            unsigned int v5 = xb[(size_t)s5 * 64 + lane];
            unsigned int v6 = xb[(size_t)s6 * 64 + lane];
            unsigned int v7 = xb[(size_t)s7 * 64 + lane];
            ax += bf2f_lo(v0) + bf2f_lo(v1) + bf2f_lo(v2) + bf2f_lo(v3)
                + bf2f_lo(v4) + bf2f_lo(v5) + bf2f_lo(v6) + bf2f_lo(v7);
            ay += bf2f_hi(v0) + bf2f_hi(v1) + bf2f_hi(v2) + bf2f_hi(v3)
                + bf2f_hi(v4) + bf2f_hi(v5) + bf2f_hi(v6) + bf2f_hi(v7);
        }
        if (j + 4 <= m) {
            int s0 = __builtin_amdgcn_readlane(idx, j + 0);
            int s1 = __builtin_amdgcn_readlane(idx, j + 1);
            int s2 = __builtin_amdgcn_readlane(idx, j + 2);
            int s3 = __builtin_amdgcn_readlane(idx, j + 3);
            unsigned int v0 = xb[(size_t)s0 * 64 + lane];
            unsigned int v1 = xb[(size_t)s1 * 64 + lane];
            unsigned int v2 = xb[(size_t)s2 * 64 + lane];
            unsigned int v3 = xb[(size_t)s3 * 64 + lane];
            ax += bf2f_lo(v0) + bf2f_lo(v1) + bf2f_lo(v2) + bf2f_lo(v3);
            ay += bf2f_hi(v0) + bf2f_hi(v1) + bf2f_hi(v2) + bf2f_hi(v3);
            j += 4;
        }
        for (; j < m; ++j) {
            int sj = __builtin_amdgcn_readlane(idx, j);
            unsigned int v = xb[(size_t)sj * 64 + lane];
            ax += bf2f_lo(v);
            ay += bf2f_hi(v);
        }
        e += m;
    }

    int deg = e1 - e0;
    float inv = 1.0f / (float)(deg > 0 ? deg : 1);
    unsigned int o = f2bf(ax * inv) | (f2bf(ay * inv) << 16);
    ((unsigned int*)sout)[((size_t)p * rows + wv) * 64 + lane] = o;
}

// ---------------- weight pre-swizzle: f32 W[128][128] -> bf16 B-frag order ----------------

__global__ __launch_bounds__(256) void k_wswz(const float* __restrict__ Wroot,
                                              const float* __restrict__ Wrel,
                                              unsigned short* __restrict__ wswz) {
    int gid = blockIdx.x * blockDim.x + threadIdx.x;   // 16*4*8*64 = 32768
    if (gid >= 16 * 4 * 8 * 64) return;
    int lane = gid & 63;
    int t = (gid >> 6) & 7;
    int c = (gid >> 9) & 3;
    int mat = gid >> 11;                 // 0..15
    int which = mat & 1;
    int pl = mat >> 1;                   // p*2 + layer
    const float* W = (which == 0 ? Wrel : Wroot) + (size_t)pl * D * D;
    int k0 = c * 32 + (lane >> 4) * 8;
    int n = t * 16 + (lane & 15);
    unsigned short o[8];
#pragma unroll
    for (int j = 0; j < 8; ++j) o[j] = (unsigned short)f2bf(W[(size_t)(k0 + j) * D + n]);
    *(uint4*)(wswz + ((size_t)((mat * 4 + c) * 8 + t) * 64 + lane) * 8) = *(uint4*)o;
}

// ---------------- MFMA GEMM: out = relu(s @ Wm + x @ Wr + b) (batched over p) ----------------

template <bool OUT_BF16>
__global__ __launch_bounds__(256) void k_mgemm(const unsigned short* __restrict__ sb,
                                               const unsigned short* __restrict__ xbase,
                                               const unsigned short* __restrict__ wswz,
                                               const float* __restrict__ bvec,
                                               void* __restrict__ outv,
                                               int M, int layer, int out_stride) {
    int p = blockIdx.y;
    int widl = (blockIdx.x * 256 + (int)threadIdx.x) >> 6;
    int lane = threadIdx.x & 63;
    int row0 = widl << 4;
    if (row0 >= M) return;
    const unsigned short* s = sb + (size_t)p * M * D;
    const unsigned short* x = xbase + (size_t)p * N_NODES * D;
    const unsigned short* wm = wswz + (size_t)((p * L_SUB + layer) * 2 + 0) * D * D;
    const unsigned short* wr = wswz + (size_t)((p * L_SUB + layer) * 2 + 1) * D * D;
    const float* bias = bvec + (size_t)(p * L_SUB + layer) * D;

    int arow = row0 + (lane & 15);
    int asub = (lane >> 4) * 8;

    union U { uint4 u; bf16x8 v; };
    f32x4 acc[8];
#pragma unroll
    for (int t = 0; t < 8; ++t) acc[t] = (f32x4){0.f, 0.f, 0.f, 0.f};

#pragma unroll
    for (int c = 0; c < 4; ++c) {
        U as, ax;
        as.u = *(const uint4*)(s + (size_t)arow * D + c * 32 + asub);
        ax.u = *(const uint4*)(x + (size_t)arow * D + c * 32 + asub);
#pragma unroll
        for (int t = 0; t < 8; ++t) {
            U bm, br;
            bm.u = *(const uint4*)(wm + ((size_t)((c * 8 + t) * 64) + lane) * 8);
            br.u = *(const uint4*)(wr + ((size_t)((c * 8 + t) * 64) + lane) * 8);
            acc[t] = __builtin_amdgcn_mfma_f32_16x16x32_bf16(as.v, bm.v, acc[t], 0, 0, 0);
            acc[t] = __builtin_amdgcn_mfma_f32_16x16x32_bf16(ax.v, br.v, acc[t], 0, 0, 0);
        }
    }

    int colb = lane & 15;
    int rq = (lane >> 4) * 4;
#pragma unroll
    for (int t = 0; t < 8; ++t) {
        int col = t * 16 + colb;
        float bv = bias[col];
#pragma unroll
        for (int r = 0; r < 4; ++r) {
            float v = fmaxf(acc[t][r] + bv, 0.f);
            size_t off = ((size_t)p * out_stride + row0 + rq + r) * D + col;
            if (OUT_BF16) ((unsigned short*)outv)[off] = (unsigned short)f2bf(v);
            else          ((float*)outv)[off] = v;
        }
    }
}

// ---------------- query = meta @ Wq + bq ----------------

__global__ void k_query(const float* __restrict__ meta, const float* __restrict__ Wq,
                        const float* __restrict__ bq, float* __restrict__ query) {
    int t = blockIdx.x * blockDim.x + threadIdx.x;
    if (t < P_MP * D) {
        int p = t >> 7, c = t & 127;
        float acc = bq[c];
        for (int k = 0; k < D_META; ++k) acc += meta[p * D_META + k] * Wq[k * D + c];
        query[t] = acc;
    }
}

// ---------------- final: per-node softmax over metapaths ----------------

__global__ __launch_bounds__(256) void k_final(const float* __restrict__ emb,
                                               const float* __restrict__ query,
                                               float* __restrict__ out) {
    int wv = (blockIdx.x * blockDim.x + threadIdx.x) >> 6;
    int lane = threadIdx.x & 63;
    if (wv >= NREG) return;
    float2 e[4];
    float sc[4];
#pragma unroll
    for (int p = 0; p < 4; ++p) {
        e[p] = *(const float2*)(emb + ((size_t)p * NREG + wv) * D + lane * 2);
        float2 q = *(const float2*)(query + p * D + lane * 2);
        float d = e[p].x * q.x + e[p].y * q.y;
#pragma unroll
        for (int o = 32; o > 0; o >>= 1) d += __shfl_xor(d, o, 64);
        sc[p] = d * SCALE_F;
    }
    float mx = fmaxf(fmaxf(sc[0], sc[1]), fmaxf(sc[2], sc[3]));
    float w[4], sum = 0.f;
#pragma unroll
    for (int p = 0; p < 4; ++p) { w[p] = __expf(sc[p] - mx); sum += w[p]; }
    float inv = 1.f / sum;
    float ox = 0.f, oy = 0.f;
#pragma unroll
    for (int p = 0; p < 4; ++p) { ox += w[p] * inv * e[p].x; oy += w[p] * inv * e[p].y; }
    float2 o; o.x = ox; o.y = oy;
    *(float2*)(out + (size_t)wv * D + lane * 2) = o;
}

// ---------------- launch ----------------

extern "C" void kernel_launch(void* const* d_in, const int* in_sizes, int n_in,
                              void* d_out, int out_size, void* d_ws, size_t ws_size,
                              hipStream_t stream) {
    const float* Etab  = (const float*)d_in[0];
    const float* meta  = (const float*)d_in[1];
    const float* Wroot = (const float*)d_in[2];   // [4][2][128][128]
    const float* Wrel  = (const float*)d_in[3];   // [4][2][128][128]
    const float* bvec  = (const float*)d_in[4];   // [4][2][128]
    const float* Wq    = (const float*)d_in[5];   // [64][128]
    const float* bq    = (const float*)d_in[6];   // [128]
    const int* edge_index = (const int*)d_in[7];  // [4][2][1600000]
    const int* eids       = (const int*)d_in[8];  // [4][100000]
    float* out = (float*)d_out;

    // workspace with lifetime aliasing:
    //   regionA (102.4 MB): pairs (CSR) -> x0 (gather..mgemmL1) -> emb (mgemmL2..final)
    char* w = (char*)d_ws;
    char* regionA = w;                           w += (size_t)P_MP * N_NODES * D * 2;     // 102.4 MB
    unsigned short* h1   = (unsigned short*)w;   w += (size_t)P_MP * N_NODES * D * 2;     // 102.4 MB
    unsigned short* sbuf = (unsigned short*)w;   w += (size_t)P_MP * N_NODES * D * 2;     // 102.4 MB
    int* ssrc = (int*)w;                         w += (size_t)P_MP * N_EDGES * 4;         // 25.6 MB
    int* offs = (int*)w;                         w += (size_t)P_MP * (N_NODES + 1) * 4 + 240;
    int* tbl  = (int*)w;                         w += (size_t)P_MP * P2N * 4;
    int* tblx = (int*)w;                         w += (size_t)P_MP * P2N * 4;
    unsigned short* wswz = (unsigned short*)w;   w += (size_t)16 * D * D * 2;             // 512 KB
    float* query = (float*)w;                    w += 4096;

    uint2* pairs       = (uint2*)regionA;          // CSR phase only (51.2 MB <= 102.4)
    unsigned short* x0 = (unsigned short*)regionA; // after p4, until mgemm L1
    float* emb         = (float*)regionA;          // written by mgemm L2 (x0 dead)

    // independent small preprocessing
    k_wswz<<<128, 256, 0, stream>>>(Wroot, Wrel, wswz);
    k_query<<<2, 256, 0, stream>>>(meta, Wq, bq, query);

    // CSR build, all 4 metapaths per launch
    p1_bhist<<<dim3(CSB, P_MP), 256, 0, stream>>>(edge_index, tbl);
    p2_scan<<<dim3(P_MP), 1024, 0, stream>>>(tbl, tblx, offs);
    p3_coarse<<<dim3(CSB, P_MP), 256, 0, stream>>>(edge_index, tblx, pairs);
    p4_fine<<<dim3(NBKT, P_MP), 256, 0, stream>>>(pairs, tblx, offs, ssrc);

    // gather (overwrites pairs region)
    k_gather<<<dim3(N_NODES * 16 / 256, P_MP), 256, 0, stream>>>(Etab, eids, x0);

    // layer 1 (M = N_NODES), all p
    k_spmm<<<dim3(N_NODES / 4, P_MP), 256, 0, stream>>>(x0, offs, ssrc, sbuf, N_NODES);
    k_mgemm<true><<<dim3((N_NODES / 16 + 3) / 4, P_MP), 256, 0, stream>>>(
        sbuf, x0, wswz, bvec, h1, N_NODES, 0, N_NODES);

    // layer 2 (M = NREG), all p (emb overwrites x0 region; x0 dead after mgemm L1)
    k_spmm<<<dim3(NREG / 4, P_MP), 256, 0, stream>>>(h1, offs, ssrc, sbuf, NREG);
    k_mgemm<false><<<dim3((NREG / 16 + 3) / 4, P_MP), 256, 0, stream>>>(
        sbuf, h1, wswz, bvec, emb, NREG, 1, NREG);

    k_final<<<(NREG * 64) / 256, 256, 0, stream>>>(emb, query, out);
}

// Round 2
// 903.016 us; speedup vs baseline: 1.2183x; 1.0045x over previous
//
#include <hip/hip_runtime.h>

#define N_NODES 100000
#define N_EDGES 1600000
#define E_TBL   200000
#define D       128
#define NREG    50000
#define P_MP    4
#define L_SUB   2
#define D_META  64
#define SCALE_F 0.08838834764831845f   // 1/sqrt(128)

// two-level counting sort geometry
#define BKT_SHIFT 9
#define BKT_NODES 512
#define NBKT      196                     // ceil(100000/512)
#define CSB       128                     // coarse-sort blocks (1.6M/128 = 12500 edges each)
#define EPB       (N_EDGES / CSB)         // 12500
#define P2N       (NBKT * CSB)            // 25088
#define P2B       (P2N / 256)             // 98

typedef __attribute__((ext_vector_type(8))) short bf16x8;
typedef __attribute__((ext_vector_type(4))) float f32x4;
typedef __attribute__((ext_vector_type(2))) float f32x2;

// ---------------- bf16 helpers ----------------

__device__ __forceinline__ float bf2f_lo(unsigned int u) {
    union { unsigned int i; float f; } v;
    v.i = u << 16;                         // low bf16 -> f32
    return v.f;
}
__device__ __forceinline__ float bf2f_hi(unsigned int u) {
    union { unsigned int i; float f; } v;
    v.i = u & 0xffff0000u;                 // high bf16 -> f32
    return v.f;
}
__device__ __forceinline__ unsigned int f2bf(float f) {
    union { float f; unsigned int i; } v;
    v.f = f;
    return (v.i + 0x7fffu + ((v.i >> 16) & 1u)) >> 16;   // RNE
}

// ---------------- CSR build (batched over p via blockIdx.y) ----------------

__global__ __launch_bounds__(256) void p1_bhist(const int* __restrict__ edge_index,
                                                int* __restrict__ tbl) {
    __shared__ int h[NBKT];
    int p = blockIdx.y, b = blockIdx.x, t = threadIdx.x;
    const int* dst = edge_index + ((size_t)p * 2 + 1) * N_EDGES;
    if (t < NBKT) h[t] = 0;
    __syncthreads();
    int e0 = b * EPB;
    for (int e = e0 + t; e < e0 + EPB; e += 256)
        atomicAdd(&h[dst[e] >> BKT_SHIFT], 1);
    __syncthreads();
    if (t < NBKT) tbl[(size_t)p * P2N + t * CSB + b] = h[t];
}

__global__ __launch_bounds__(1024) void p2_scan(const int* __restrict__ tbl,
                                                int* __restrict__ tblx,
                                                int* __restrict__ offs) {
    __shared__ int ts[1024];
    int p = blockIdx.x, t = threadIdx.x;
    const int* tp = tbl + (size_t)p * P2N;
    int* xp = tblx + (size_t)p * P2N;
    int v[25];
    int base = t * 25;
    int sum = 0;
#pragma unroll
    for (int i = 0; i < 25; ++i) {
        int idx = base + i;
        int val = (idx < P2N) ? tp[idx] : 0;
        v[i] = val;
        sum += val;
    }
    ts[t] = sum;
    __syncthreads();
    for (int o = 1; o < 1024; o <<= 1) {
        int u = (t >= o) ? ts[t - o] : 0;
        __syncthreads();
        ts[t] += u;
        __syncthreads();
    }
    int run = ts[t] - sum;
#pragma unroll
    for (int i = 0; i < 25; ++i) {
        int idx = base + i;
        if (idx < P2N) xp[idx] = run;
        run += v[i];
    }
    if (t == 0) offs[(size_t)p * (N_NODES + 1) + N_NODES] = N_EDGES;
}

__global__ __launch_bounds__(256) void p3_coarse(const int* __restrict__ edge_index,
                                                 const int* __restrict__ tblx,
                                                 uint2* __restrict__ pairs) {
    __shared__ int lcur[NBKT];
    int p = blockIdx.y, b = blockIdx.x, t = threadIdx.x;
    const int* src = edge_index + ((size_t)p * 2 + 0) * N_EDGES;
    const int* dst = edge_index + ((size_t)p * 2 + 1) * N_EDGES;
    const int* txp = tblx + (size_t)p * P2N;
    uint2* pp = pairs + (size_t)p * N_EDGES;
    if (t < NBKT) lcur[t] = txp[t * CSB + b];
    __syncthreads();
    int e0 = b * EPB;
    for (int e = e0 + t; e < e0 + EPB; e += 256) {
        int d = dst[e], s0 = src[e];
        int pos = atomicAdd(&lcur[d >> BKT_SHIFT], 1);
        pp[pos] = make_uint2((unsigned)s0, (unsigned)d);
    }
}

__global__ __launch_bounds__(256) void p4_fine(const uint2* __restrict__ pairs,
                                               const int* __restrict__ tblx,
                                               int* __restrict__ offs,
                                               int* __restrict__ ssrc) {
    __shared__ int lhist[BKT_NODES];
    __shared__ int lcur[BKT_NODES];
    __shared__ int pr[256];
    int p = blockIdx.y, b = blockIdx.x, t = threadIdx.x;
    const uint2* pp = pairs + (size_t)p * N_EDGES;
    const int* txp = tblx + (size_t)p * P2N;
    int* offp = offs + (size_t)p * (N_NODES + 1);
    int* sp = ssrc + (size_t)p * N_EDGES;
    int nbase = b << BKT_SHIFT;
    int e0 = txp[b * CSB];
    int e1 = (b + 1 < NBKT) ? txp[(b + 1) * CSB] : N_EDGES;
    lhist[t] = 0;
    lhist[t + 256] = 0;
    __syncthreads();
    for (int e = e0 + t; e < e1; e += 256)
        atomicAdd(&lhist[pp[e].y - nbase], 1);
    __syncthreads();
    int c0 = lhist[2 * t], c1 = lhist[2 * t + 1];
    int ps = c0 + c1;
    pr[t] = ps;
    __syncthreads();
    for (int o = 1; o < 256; o <<= 1) {
        int u = (t >= o) ? pr[t - o] : 0;
        __syncthreads();
        pr[t] += u;
        __syncthreads();
    }
    int ex = e0 + pr[t] - ps;
    lcur[2 * t] = ex;
    lcur[2 * t + 1] = ex + c0;
    int n0 = nbase + 2 * t;
    if (n0 < N_NODES)     offp[n0] = ex;
    if (n0 + 1 < N_NODES) offp[n0 + 1] = ex + c0;
    __syncthreads();
    for (int e = e0 + t; e < e1; e += 256) {
        uint2 q = pp[e];
        int pos = atomicAdd(&lcur[q.y - nbase], 1);
        sp[pos] = (int)q.x;
    }
}

// ---------------- gather x0 = bf16(E[eids]) (batched over p) ----------------

__global__ __launch_bounds__(256) void k_gather(const float* __restrict__ Etab,
                                                const int* __restrict__ eids,
                                                unsigned short* __restrict__ x0) {
    int p = blockIdx.y;
    int i = blockIdx.x * 256 + threadIdx.x;
    int n = i >> 4, g = i & 15;
    if (n >= N_NODES) return;
    int r = eids[(size_t)p * N_NODES + n];
    const float4* srcp = (const float4*)(Etab + (size_t)r * D + g * 8);
    float4 a = srcp[0], b = srcp[1];
    uint4 o;
    o.x = f2bf(a.x) | (f2bf(a.y) << 16);
    o.y = f2bf(a.z) | (f2bf(a.w) << 16);
    o.z = f2bf(b.x) | (f2bf(b.y) << 16);
    o.w = f2bf(b.z) | (f2bf(b.w) << 16);
    *(uint4*)(x0 + ((size_t)p * N_NODES + n) * D + g * 8) = o;
}

// ---------------- SpMM: quarter-wave rows, 4 edges per VMEM instruction ----------------
// 16 lanes x dwordx4 cover one 256B row. One global_load_dwordx4 serves 4 edges
// (one per quarter-wave). Indices distributed via ds_bpermute (1 per 4 edges).
// f32x2 accumulators -> v_pk_add_f32. Cross-quarter reduce at the end.

__device__ __forceinline__ void acc4(uint4 r, f32x2& a01, f32x2& a23, f32x2& a45, f32x2& a67) {
    f32x2 t;
    t.x = bf2f_lo(r.x); t.y = bf2f_hi(r.x); a01 += t;
    t.x = bf2f_lo(r.y); t.y = bf2f_hi(r.y); a23 += t;
    t.x = bf2f_lo(r.z); t.y = bf2f_hi(r.z); a45 += t;
    t.x = bf2f_lo(r.w); t.y = bf2f_hi(r.w); a67 += t;
}

__global__ __launch_bounds__(256) void k_spmm(const unsigned short* __restrict__ x,
                                              const int* __restrict__ offs,
                                              const int* __restrict__ ssrc,
                                              unsigned short* __restrict__ sout, int rows) {
    int p = blockIdx.y;
    int lane = threadIdx.x & 63;
    int wv = __builtin_amdgcn_readfirstlane((blockIdx.x * 256 + (int)threadIdx.x) >> 6);
    if (wv >= rows) return;
    const int* offp = offs + (size_t)p * (N_NODES + 1);
    const int* ep = ssrc + (size_t)p * N_EDGES;
    const char* xbb = (const char*)x + (size_t)p * N_NODES * 256;
    int e0 = __builtin_amdgcn_readfirstlane(offp[wv]);
    int e1 = __builtin_amdgcn_readfirstlane(offp[wv + 1]);

    int qb   = (lane >> 4) << 2;          // bpermute byte-addr base for this quarter
    unsigned lo16 = (unsigned)(lane & 15) << 4;   // byte offset within row

    f32x2 a01 = {0.f, 0.f}, a23 = {0.f, 0.f}, a45 = {0.f, 0.f}, a67 = {0.f, 0.f};

    int e = e0;
    while (e < e1) {
        int m = min(64, e1 - e);
        int v = (lane < m) ? ep[e + lane] : 0;     // one coalesced index load (64 edges)
        int m4 = m >> 2;
        int k = 0;
        for (; k + 4 <= m4; k += 4) {
            int i0 = __builtin_amdgcn_ds_bpermute(qb + ((k + 0) << 4), v);
            int i1 = __builtin_amdgcn_ds_bpermute(qb + ((k + 1) << 4), v);
            int i2 = __builtin_amdgcn_ds_bpermute(qb + ((k + 2) << 4), v);
            int i3 = __builtin_amdgcn_ds_bpermute(qb + ((k + 3) << 4), v);
            uint4 r0 = *(const uint4*)(xbb + ((((unsigned)i0) << 8) | lo16));
            uint4 r1 = *(const uint4*)(xbb + ((((unsigned)i1) << 8) | lo16));
            uint4 r2 = *(const uint4*)(xbb + ((((unsigned)i2) << 8) | lo16));
            uint4 r3 = *(const uint4*)(xbb + ((((unsigned)i3) << 8) | lo16));
            acc4(r0, a01, a23, a45, a67);
            acc4(r1, a01, a23, a45, a67);
            acc4(r2, a01, a23, a45, a67);
            acc4(r3, a01, a23, a45, a67);
        }
        for (; k < m4; ++k) {
            int i0 = __builtin_amdgcn_ds_bpermute(qb + (k << 4), v);
            uint4 r0 = *(const uint4*)(xbb + ((((unsigned)i0) << 8) | lo16));
            acc4(r0, a01, a23, a45, a67);
        }
        int rem = m & 3;
        if (rem) {
            int iv = __builtin_amdgcn_ds_bpermute(qb + (m4 << 4), v);
            if ((lane >> 4) < rem) {
                uint4 r = *(const uint4*)(xbb + ((((unsigned)iv) << 8) | lo16));
                acc4(r, a01, a23, a45, a67);
            }
        }
        e += m;
    }

    // cross-quarter reduction: lanes {l, l+16, l+32, l+48} hold the same 8 cols
#pragma unroll
    for (int o = 32; o >= 16; o >>= 1) {
        f32x2 t;
        t.x = __shfl_xor(a01.x, o, 64); t.y = __shfl_xor(a01.y, o, 64); a01 += t;
        t.x = __shfl_xor(a23.x, o, 64); t.y = __shfl_xor(a23.y, o, 64); a23 += t;
        t.x = __shfl_xor(a45.x, o, 64); t.y = __shfl_xor(a45.y, o, 64); a45 += t;
        t.x = __shfl_xor(a67.x, o, 64); t.y = __shfl_xor(a67.y, o, 64); a67 += t;
    }

    int deg = e1 - e0;
    float inv = 1.0f / (float)(deg > 0 ? deg : 1);
    if (lane < 16) {
        uint4 o;
        o.x = f2bf(a01.x * inv) | (f2bf(a01.y * inv) << 16);
        o.y = f2bf(a23.x * inv) | (f2bf(a23.y * inv) << 16);
        o.z = f2bf(a45.x * inv) | (f2bf(a45.y * inv) << 16);
        o.w = f2bf(a67.x * inv) | (f2bf(a67.y * inv) << 16);
        *(uint4*)((char*)sout + ((size_t)p * rows + wv) * 256 + lo16) = o;
    }
}

// ---------------- weight pre-swizzle: f32 W[128][128] -> bf16 B-frag order ----------------

__global__ __launch_bounds__(256) void k_wswz(const float* __restrict__ Wroot,
                                              const float* __restrict__ Wrel,
                                              unsigned short* __restrict__ wswz) {
    int gid = blockIdx.x * blockDim.x + threadIdx.x;   // 16*4*8*64 = 32768
    if (gid >= 16 * 4 * 8 * 64) return;
    int lane = gid & 63;
    int t = (gid >> 6) & 7;
    int c = (gid >> 9) & 3;
    int mat = gid >> 11;                 // 0..15
    int which = mat & 1;
    int pl = mat >> 1;                   // p*2 + layer
    const float* W = (which == 0 ? Wrel : Wroot) + (size_t)pl * D * D;
    int k0 = c * 32 + (lane >> 4) * 8;
    int n = t * 16 + (lane & 15);
    unsigned short o[8];
#pragma unroll
    for (int j = 0; j < 8; ++j) o[j] = (unsigned short)f2bf(W[(size_t)(k0 + j) * D + n]);
    *(uint4*)(wswz + ((size_t)((mat * 4 + c) * 8 + t) * 64 + lane) * 8) = *(uint4*)o;
}

// ---------------- MFMA GEMM: out = relu(s @ Wm + x @ Wr + b) (batched over p) ----------------

template <bool OUT_BF16>
__global__ __launch_bounds__(256) void k_mgemm(const unsigned short* __restrict__ sb,
                                               const unsigned short* __restrict__ xbase,
                                               const unsigned short* __restrict__ wswz,
                                               const float* __restrict__ bvec,
                                               void* __restrict__ outv,
                                               int M, int layer, int out_stride) {
    int p = blockIdx.y;
    int widl = (blockIdx.x * 256 + (int)threadIdx.x) >> 6;
    int lane = threadIdx.x & 63;
    int row0 = widl << 4;
    if (row0 >= M) return;
    const unsigned short* s = sb + (size_t)p * M * D;
    const unsigned short* x = xbase + (size_t)p * N_NODES * D;
    const unsigned short* wm = wswz + (size_t)((p * L_SUB + layer) * 2 + 0) * D * D;
    const unsigned short* wr = wswz + (size_t)((p * L_SUB + layer) * 2 + 1) * D * D;
    const float* bias = bvec + (size_t)(p * L_SUB + layer) * D;

    int arow = row0 + (lane & 15);
    int asub = (lane >> 4) * 8;

    union U { uint4 u; bf16x8 v; };
    f32x4 acc[8];
#pragma unroll
    for (int t = 0; t < 8; ++t) acc[t] = (f32x4){0.f, 0.f, 0.f, 0.f};

#pragma unroll
    for (int c = 0; c < 4; ++c) {
        U as, ax;
        as.u = *(const uint4*)(s + (size_t)arow * D + c * 32 + asub);
        ax.u = *(const uint4*)(x + (size_t)arow * D + c * 32 + asub);
#pragma unroll
        for (int t = 0; t < 8; ++t) {
            U bm, br;
            bm.u = *(const uint4*)(wm + ((size_t)((c * 8 + t) * 64) + lane) * 8);
            br.u = *(const uint4*)(wr + ((size_t)((c * 8 + t) * 64) + lane) * 8);
            acc[t] = __builtin_amdgcn_mfma_f32_16x16x32_bf16(as.v, bm.v, acc[t], 0, 0, 0);
            acc[t] = __builtin_amdgcn_mfma_f32_16x16x32_bf16(ax.v, br.v, acc[t], 0, 0, 0);
        }
    }

    int colb = lane & 15;
    int rq = (lane >> 4) * 4;
#pragma unroll
    for (int t = 0; t < 8; ++t) {
        int col = t * 16 + colb;
        float bv = bias[col];
#pragma unroll
        for (int r = 0; r < 4; ++r) {
            float v = fmaxf(acc[t][r] + bv, 0.f);
            size_t off = ((size_t)p * out_stride + row0 + rq + r) * D + col;
            if (OUT_BF16) ((unsigned short*)outv)[off] = (unsigned short)f2bf(v);
            else          ((float*)outv)[off] = v;
        }
    }
}

// ---------------- query = meta @ Wq + bq ----------------

__global__ void k_query(const float* __restrict__ meta, const float* __restrict__ Wq,
                        const float* __restrict__ bq, float* __restrict__ query) {
    int t = blockIdx.x * blockDim.x + threadIdx.x;
    if (t < P_MP * D) {
        int p = t >> 7, c = t & 127;
        float acc = bq[c];
        for (int k = 0; k < D_META; ++k) acc += meta[p * D_META + k] * Wq[k * D + c];
        query[t] = acc;
    }
}

// ---------------- final: per-node softmax over metapaths ----------------

__global__ __launch_bounds__(256) void k_final(const float* __restrict__ emb,
                                               const float* __restrict__ query,
                                               float* __restrict__ out) {
    int wv = (blockIdx.x * blockDim.x + threadIdx.x) >> 6;
    int lane = threadIdx.x & 63;
    if (wv >= NREG) return;
    float2 e[4];
    float sc[4];
#pragma unroll
    for (int p = 0; p < 4; ++p) {
        e[p] = *(const float2*)(emb + ((size_t)p * NREG + wv) * D + lane * 2);
        float2 q = *(const float2*)(query + p * D + lane * 2);
        float d = e[p].x * q.x + e[p].y * q.y;
#pragma unroll
        for (int o = 32; o > 0; o >>= 1) d += __shfl_xor(d, o, 64);
        sc[p] = d * SCALE_F;
    }
    float mx = fmaxf(fmaxf(sc[0], sc[1]), fmaxf(sc[2], sc[3]));
    float w[4], sum = 0.f;
#pragma unroll
    for (int p = 0; p < 4; ++p) { w[p] = __expf(sc[p] - mx); sum += w[p]; }
    float inv = 1.f / sum;
    float ox = 0.f, oy = 0.f;
#pragma unroll
    for (int p = 0; p < 4; ++p) { ox += w[p] * inv * e[p].x; oy += w[p] * inv * e[p].y; }
    float2 o; o.x = ox; o.y = oy;
    *(float2*)(out + (size_t)wv * D + lane * 2) = o;
}

// ---------------- launch ----------------

extern "C" void kernel_launch(void* const* d_in, const int* in_sizes, int n_in,
                              void* d_out, int out_size, void* d_ws, size_t ws_size,
                              hipStream_t stream) {
    const float* Etab  = (const float*)d_in[0];
    const float* meta  = (const float*)d_in[1];
    const float* Wroot = (const float*)d_in[2];   // [4][2][128][128]
    const float* Wrel  = (const float*)d_in[3];   // [4][2][128][128]
    const float* bvec  = (const float*)d_in[4];   // [4][2][128]
    const float* Wq    = (const float*)d_in[5];   // [64][128]
    const float* bq    = (const float*)d_in[6];   // [128]
    const int* edge_index = (const int*)d_in[7];  // [4][2][1600000]
    const int* eids       = (const int*)d_in[8];  // [4][100000]
    float* out = (float*)d_out;

    char* w = (char*)d_ws;
    char* regionA = w;                           w += (size_t)P_MP * N_NODES * D * 2;     // 102.4 MB
    unsigned short* h1   = (unsigned short*)w;   w += (size_t)P_MP * N_NODES * D * 2;     // 102.4 MB
    unsigned short* sbuf = (unsigned short*)w;   w += (size_t)P_MP * N_NODES * D * 2;     // 102.4 MB
    int* ssrc = (int*)w;                         w += (size_t)P_MP * N_EDGES * 4;         // 25.6 MB
    int* offs = (int*)w;                         w += (size_t)P_MP * (N_NODES + 1) * 4 + 240;
    int* tbl  = (int*)w;                         w += (size_t)P_MP * P2N * 4;
    int* tblx = (int*)w;                         w += (size_t)P_MP * P2N * 4;
    unsigned short* wswz = (unsigned short*)w;   w += (size_t)16 * D * D * 2;             // 512 KB
    float* query = (float*)w;                    w += 4096;

    uint2* pairs       = (uint2*)regionA;          // CSR phase only
    unsigned short* x0 = (unsigned short*)regionA; // after p4, until mgemm L1
    float* emb         = (float*)regionA;          // written by mgemm L2 (x0 dead)

    k_wswz<<<128, 256, 0, stream>>>(Wroot, Wrel, wswz);
    k_query<<<2, 256, 0, stream>>>(meta, Wq, bq, query);

    p1_bhist<<<dim3(CSB, P_MP), 256, 0, stream>>>(edge_index, tbl);
    p2_scan<<<dim3(P_MP), 1024, 0, stream>>>(tbl, tblx, offs);
    p3_coarse<<<dim3(CSB, P_MP), 256, 0, stream>>>(edge_index, tblx, pairs);
    p4_fine<<<dim3(NBKT, P_MP), 256, 0, stream>>>(pairs, tblx, offs, ssrc);

    k_gather<<<dim3(N_NODES * 16 / 256, P_MP), 256, 0, stream>>>(Etab, eids, x0);

    k_spmm<<<dim3(N_NODES / 4, P_MP), 256, 0, stream>>>(x0, offs, ssrc, sbuf, N_NODES);
    k_mgemm<true><<<dim3((N_NODES / 16 + 3) / 4, P_MP), 256, 0, stream>>>(
        sbuf, x0, wswz, bvec, h1, N_NODES, 0, N_NODES);

    k_spmm<<<dim3(NREG / 4, P_MP), 256, 0, stream>>>(h1, offs, ssrc, sbuf, NREG);
    k_mgemm<false><<<dim3((NREG / 16 + 3) / 4, P_MP), 256, 0, stream>>>(
        sbuf, h1, wswz, bvec, emb, NREG, 1, NREG);

    k_final<<<(NREG * 64) / 256, 256, 0, stream>>>(emb, query, out);
}

// Round 3
// 843.251 us; speedup vs baseline: 1.3047x; 1.0709x over previous
//
#include <hip/hip_runtime.h>

#define N_NODES 100000
#define N_EDGES 1600000
#define E_TBL   200000
#define D       128
#define NREG    50000
#define P_MP    4
#define L_SUB   2
#define D_META  64
#define SCALE_F 0.08838834764831845f   // 1/sqrt(128)

// two-level counting sort geometry
#define BKT_SHIFT 9
#define BKT_NODES 512
#define NBKT      196                     // ceil(100000/512)
#define CSB       128                     // coarse-sort blocks (1.6M/128 = 12500 edges each)
#define EPB       (N_EDGES / CSB)         // 12500
#define P2N       (NBKT * CSB)            // 25088

typedef __attribute__((ext_vector_type(8))) short bf16x8;
typedef __attribute__((ext_vector_type(4))) float f32x4;
typedef __attribute__((ext_vector_type(2))) float f32x2;

// ---------------- bf16 helpers ----------------

__device__ __forceinline__ float bf2f_lo(unsigned int u) {
    union { unsigned int i; float f; } v;
    v.i = u << 16;
    return v.f;
}
__device__ __forceinline__ float bf2f_hi(unsigned int u) {
    union { unsigned int i; float f; } v;
    v.i = u & 0xffff0000u;
    return v.f;
}
__device__ __forceinline__ unsigned int f2bf(float f) {
    union { float f; unsigned int i; } v;
    v.f = f;
    return (v.i + 0x7fffu + ((v.i >> 16) & 1u)) >> 16;   // RNE
}

// ---------------- CSR build (batched over p via blockIdx.y) ----------------

__global__ __launch_bounds__(256) void p1_bhist(const int* __restrict__ edge_index,
                                                int* __restrict__ tbl) {
    __shared__ int h[NBKT];
    int p = blockIdx.y, b = blockIdx.x, t = threadIdx.x;
    const int* dst = edge_index + ((size_t)p * 2 + 1) * N_EDGES;
    if (t < NBKT) h[t] = 0;
    __syncthreads();
    int e0 = b * EPB;
    for (int e = e0 + t; e < e0 + EPB; e += 256)
        atomicAdd(&h[dst[e] >> BKT_SHIFT], 1);
    __syncthreads();
    if (t < NBKT) tbl[(size_t)p * P2N + t * CSB + b] = h[t];
}

__global__ __launch_bounds__(1024) void p2_scan(const int* __restrict__ tbl,
                                                int* __restrict__ tblx,
                                                int* __restrict__ offs) {
    __shared__ int ts[1024];
    int p = blockIdx.x, t = threadIdx.x;
    const int* tp = tbl + (size_t)p * P2N;
    int* xp = tblx + (size_t)p * P2N;
    int v[25];
    int base = t * 25;
    int sum = 0;
#pragma unroll
    for (int i = 0; i < 25; ++i) {
        int idx = base + i;
        int val = (idx < P2N) ? tp[idx] : 0;
        v[i] = val;
        sum += val;
    }
    ts[t] = sum;
    __syncthreads();
    for (int o = 1; o < 1024; o <<= 1) {
        int u = (t >= o) ? ts[t - o] : 0;
        __syncthreads();
        ts[t] += u;
        __syncthreads();
    }
    int run = ts[t] - sum;
#pragma unroll
    for (int i = 0; i < 25; ++i) {
        int idx = base + i;
        if (idx < P2N) xp[idx] = run;
        run += v[i];
    }
    if (t == 0) offs[(size_t)p * (N_NODES + 1) + N_NODES] = N_EDGES;
}

__global__ __launch_bounds__(256) void p3_coarse(const int* __restrict__ edge_index,
                                                 const int* __restrict__ tblx,
                                                 uint2* __restrict__ pairs) {
    __shared__ int lcur[NBKT];
    int p = blockIdx.y, b = blockIdx.x, t = threadIdx.x;
    const int* src = edge_index + ((size_t)p * 2 + 0) * N_EDGES;
    const int* dst = edge_index + ((size_t)p * 2 + 1) * N_EDGES;
    const int* txp = tblx + (size_t)p * P2N;
    uint2* pp = pairs + (size_t)p * N_EDGES;
    if (t < NBKT) lcur[t] = txp[t * CSB + b];
    __syncthreads();
    int e0 = b * EPB;
    for (int e = e0 + t; e < e0 + EPB; e += 256) {
        int d = dst[e], s0 = src[e];
        int pos = atomicAdd(&lcur[d >> BKT_SHIFT], 1);
        pp[pos] = make_uint2((unsigned)s0, (unsigned)d);
    }
}

__global__ __launch_bounds__(256) void p4_fine(const uint2* __restrict__ pairs,
                                               const int* __restrict__ tblx,
                                               int* __restrict__ offs,
                                               int* __restrict__ ssrc) {
    __shared__ int lhist[BKT_NODES];
    __shared__ int lcur[BKT_NODES];
    __shared__ int pr[256];
    int p = blockIdx.y, b = blockIdx.x, t = threadIdx.x;
    const uint2* pp = pairs + (size_t)p * N_EDGES;
    const int* txp = tblx + (size_t)p * P2N;
    int* offp = offs + (size_t)p * (N_NODES + 1);
    int* sp = ssrc + (size_t)p * N_EDGES;
    int nbase = b << BKT_SHIFT;
    int e0 = txp[b * CSB];
    int e1 = (b + 1 < NBKT) ? txp[(b + 1) * CSB] : N_EDGES;
    lhist[t] = 0;
    lhist[t + 256] = 0;
    __syncthreads();
    for (int e = e0 + t; e < e1; e += 256)
        atomicAdd(&lhist[pp[e].y - nbase], 1);
    __syncthreads();
    int c0 = lhist[2 * t], c1 = lhist[2 * t + 1];
    int ps = c0 + c1;
    pr[t] = ps;
    __syncthreads();
    for (int o = 1; o < 256; o <<= 1) {
        int u = (t >= o) ? pr[t - o] : 0;
        __syncthreads();
        pr[t] += u;
        __syncthreads();
    }
    int ex = e0 + pr[t] - ps;
    lcur[2 * t] = ex;
    lcur[2 * t + 1] = ex + c0;
    int n0 = nbase + 2 * t;
    if (n0 < N_NODES)     offp[n0] = ex;
    if (n0 + 1 < N_NODES) offp[n0 + 1] = ex + c0;
    __syncthreads();
    for (int e = e0 + t; e < e1; e += 256) {
        uint2 q = pp[e];
        int pos = atomicAdd(&lcur[q.y - nbase], 1);
        sp[pos] = (int)q.x;
    }
}

// ---------------- gather x0 = bf16(E[eids]) (batched over p) ----------------

__global__ __launch_bounds__(256) void k_gather(const float* __restrict__ Etab,
                                                const int* __restrict__ eids,
                                                unsigned short* __restrict__ x0) {
    int p = blockIdx.y;
    int i = blockIdx.x * 256 + threadIdx.x;
    int n = i >> 4, g = i & 15;
    if (n >= N_NODES) return;
    int r = eids[(size_t)p * N_NODES + n];
    const float4* srcp = (const float4*)(Etab + (size_t)r * D + g * 8);
    float4 a = srcp[0], b = srcp[1];
    uint4 o;
    o.x = f2bf(a.x) | (f2bf(a.y) << 16);
    o.y = f2bf(a.z) | (f2bf(a.w) << 16);
    o.z = f2bf(b.x) | (f2bf(b.y) << 16);
    o.w = f2bf(b.z) | (f2bf(b.w) << 16);
    *(uint4*)(x0 + ((size_t)p * N_NODES + n) * D + g * 8) = o;
}

// ---------------- weight pre-swizzle: f32 W[128][128] -> bf16 B-frag order ----------------

__global__ __launch_bounds__(256) void k_wswz(const float* __restrict__ Wroot,
                                              const float* __restrict__ Wrel,
                                              unsigned short* __restrict__ wswz) {
    int gid = blockIdx.x * blockDim.x + threadIdx.x;   // 16*4*8*64 = 32768
    if (gid >= 16 * 4 * 8 * 64) return;
    int lane = gid & 63;
    int t = (gid >> 6) & 7;
    int c = (gid >> 9) & 3;
    int mat = gid >> 11;                 // 0..15
    int which = mat & 1;
    int pl = mat >> 1;                   // p*2 + layer
    const float* W = (which == 0 ? Wrel : Wroot) + (size_t)pl * D * D;
    int k0 = c * 32 + (lane >> 4) * 8;
    int n = t * 16 + (lane & 15);
    unsigned short o[8];
#pragma unroll
    for (int j = 0; j < 8; ++j) o[j] = (unsigned short)f2bf(W[(size_t)(k0 + j) * D + n]);
    *(uint4*)(wswz + ((size_t)((mat * 4 + c) * 8 + t) * 64 + lane) * 8) = *(uint4*)o;
}

// ---------------- fused SpMM + dual-GEMM ----------------
// Block = 4 waves = 16 dst rows. Phase 1: wave w aggregates dsts row0+4w..+3
// (quarter-wave gather, 4 edges per VMEM inst), stages bf16 rows in LDS
// (272B stride -> 2-way bank aliasing, free). Phase 2: wave w computes
// col-tiles {2w, 2w+1} of relu(s@Wm + x@Wr + b) via 16 MFMA.

__device__ __forceinline__ void acc4(uint4 r, f32x2& a01, f32x2& a23, f32x2& a45, f32x2& a67) {
    f32x2 t;
    t.x = bf2f_lo(r.x); t.y = bf2f_hi(r.x); a01 += t;
    t.x = bf2f_lo(r.y); t.y = bf2f_hi(r.y); a23 += t;
    t.x = bf2f_lo(r.z); t.y = bf2f_hi(r.z); a45 += t;
    t.x = bf2f_lo(r.w); t.y = bf2f_hi(r.w); a67 += t;
}

template <bool OUT_BF16>
__global__ __launch_bounds__(256) void k_fused(const unsigned short* __restrict__ x,
                                               const int* __restrict__ offs,
                                               const int* __restrict__ ssrc,
                                               const unsigned short* __restrict__ wswz,
                                               const float* __restrict__ bvec,
                                               void* __restrict__ outv,
                                               int layer, int out_stride) {
    __shared__ __align__(16) unsigned short srow[16 * 136];   // 272B row stride
    int p = blockIdx.y;
    int w = (int)(threadIdx.x >> 6);
    int lane = (int)(threadIdx.x & 63);
    int row0 = (int)blockIdx.x << 4;
    const int* offp = offs + (size_t)p * (N_NODES + 1);
    const int* ep = ssrc + (size_t)p * N_EDGES;
    const char* xbb = (const char*)x + (size_t)p * N_NODES * 256;
    int qb = (lane >> 4) << 2;
    unsigned lo16 = (unsigned)(lane & 15) << 4;

    // ---- phase 1: aggregate 4 dst rows per wave ----
    for (int i = 0; i < 4; ++i) {
        int dst = row0 + w * 4 + i;
        int e0 = __builtin_amdgcn_readfirstlane(offp[dst]);
        int e1 = __builtin_amdgcn_readfirstlane(offp[dst + 1]);
        f32x2 a01 = {0.f, 0.f}, a23 = {0.f, 0.f}, a45 = {0.f, 0.f}, a67 = {0.f, 0.f};
        int e = e0;
        while (e < e1) {
            int m = min(64, e1 - e);
            int v = (lane < m) ? ep[e + lane] : 0;
            int m4 = m >> 2;
            int k = 0;
            for (; k + 4 <= m4; k += 4) {
                int i0 = __builtin_amdgcn_ds_bpermute(qb + ((k + 0) << 4), v);
                int i1 = __builtin_amdgcn_ds_bpermute(qb + ((k + 1) << 4), v);
                int i2 = __builtin_amdgcn_ds_bpermute(qb + ((k + 2) << 4), v);
                int i3 = __builtin_amdgcn_ds_bpermute(qb + ((k + 3) << 4), v);
                uint4 r0 = *(const uint4*)(xbb + ((((unsigned)i0) << 8) | lo16));
                uint4 r1 = *(const uint4*)(xbb + ((((unsigned)i1) << 8) | lo16));
                uint4 r2 = *(const uint4*)(xbb + ((((unsigned)i2) << 8) | lo16));
                uint4 r3 = *(const uint4*)(xbb + ((((unsigned)i3) << 8) | lo16));
                acc4(r0, a01, a23, a45, a67);
                acc4(r1, a01, a23, a45, a67);
                acc4(r2, a01, a23, a45, a67);
                acc4(r3, a01, a23, a45, a67);
            }
            for (; k < m4; ++k) {
                int i0 = __builtin_amdgcn_ds_bpermute(qb + (k << 4), v);
                uint4 r0 = *(const uint4*)(xbb + ((((unsigned)i0) << 8) | lo16));
                acc4(r0, a01, a23, a45, a67);
            }
            int rem = m & 3;
            if (rem) {
                int iv = __builtin_amdgcn_ds_bpermute(qb + (m4 << 4), v);
                if ((lane >> 4) < rem) {
                    uint4 r = *(const uint4*)(xbb + ((((unsigned)iv) << 8) | lo16));
                    acc4(r, a01, a23, a45, a67);
                }
            }
            e += m;
        }
#pragma unroll
        for (int o = 32; o >= 16; o >>= 1) {
            f32x2 t;
            t.x = __shfl_xor(a01.x, o, 64); t.y = __shfl_xor(a01.y, o, 64); a01 += t;
            t.x = __shfl_xor(a23.x, o, 64); t.y = __shfl_xor(a23.y, o, 64); a23 += t;
            t.x = __shfl_xor(a45.x, o, 64); t.y = __shfl_xor(a45.y, o, 64); a45 += t;
            t.x = __shfl_xor(a67.x, o, 64); t.y = __shfl_xor(a67.y, o, 64); a67 += t;
        }
        int deg = e1 - e0;
        float inv = 1.0f / (float)(deg > 0 ? deg : 1);
        if (lane < 16) {
            uint4 o4;
            o4.x = f2bf(a01.x * inv) | (f2bf(a01.y * inv) << 16);
            o4.y = f2bf(a23.x * inv) | (f2bf(a23.y * inv) << 16);
            o4.z = f2bf(a45.x * inv) | (f2bf(a45.y * inv) << 16);
            o4.w = f2bf(a67.x * inv) | (f2bf(a67.y * inv) << 16);
            *(uint4*)((char*)srow + (w * 4 + i) * 272 + lo16) = o4;
        }
    }
    __syncthreads();

    // ---- phase 2: dual GEMM on the 16 staged rows ----
    const unsigned short* wm = wswz + (size_t)((p * L_SUB + layer) * 2 + 0) * D * D;
    const unsigned short* wr = wswz + (size_t)((p * L_SUB + layer) * 2 + 1) * D * D;
    const float* bias = bvec + (size_t)(p * L_SUB + layer) * D;
    int rl = lane & 15;
    int asub = (lane >> 4) * 8;
    const unsigned short* xrow = x + (size_t)p * N_NODES * D + (size_t)(row0 + rl) * D;

    union U { uint4 u; bf16x8 v; };
    f32x4 acc0 = (f32x4){0.f, 0.f, 0.f, 0.f};
    f32x4 acc1 = (f32x4){0.f, 0.f, 0.f, 0.f};
    int t0 = w * 2;
#pragma unroll
    for (int c = 0; c < 4; ++c) {
        U as, ax;
        as.u = *(const uint4*)((const char*)srow + rl * 272 + c * 64 + ((lane >> 4) << 4));
        ax.u = *(const uint4*)(xrow + c * 32 + asub);
        U b0m, b0r, b1m, b1r;
        b0m.u = *(const uint4*)(wm + ((size_t)((c * 8 + t0) * 64) + lane) * 8);
        b0r.u = *(const uint4*)(wr + ((size_t)((c * 8 + t0) * 64) + lane) * 8);
        b1m.u = *(const uint4*)(wm + ((size_t)((c * 8 + t0 + 1) * 64) + lane) * 8);
        b1r.u = *(const uint4*)(wr + ((size_t)((c * 8 + t0 + 1) * 64) + lane) * 8);
        acc0 = __builtin_amdgcn_mfma_f32_16x16x32_bf16(as.v, b0m.v, acc0, 0, 0, 0);
        acc0 = __builtin_amdgcn_mfma_f32_16x16x32_bf16(ax.v, b0r.v, acc0, 0, 0, 0);
        acc1 = __builtin_amdgcn_mfma_f32_16x16x32_bf16(as.v, b1m.v, acc1, 0, 0, 0);
        acc1 = __builtin_amdgcn_mfma_f32_16x16x32_bf16(ax.v, b1r.v, acc1, 0, 0, 0);
    }

    int rq = (lane >> 4) * 4;
#pragma unroll
    for (int tt = 0; tt < 2; ++tt) {
        f32x4 a = tt ? acc1 : acc0;
        int col = (t0 + tt) * 16 + rl;
        float bv = bias[col];
#pragma unroll
        for (int r = 0; r < 4; ++r) {
            float v = fmaxf(a[r] + bv, 0.f);
            size_t off = ((size_t)p * out_stride + row0 + rq + r) * D + col;
            if (OUT_BF16) ((unsigned short*)outv)[off] = (unsigned short)f2bf(v);
            else          ((float*)outv)[off] = v;
        }
    }
}

// ---------------- query = meta @ Wq + bq ----------------

__global__ void k_query(const float* __restrict__ meta, const float* __restrict__ Wq,
                        const float* __restrict__ bq, float* __restrict__ query) {
    int t = blockIdx.x * blockDim.x + threadIdx.x;
    if (t < P_MP * D) {
        int p = t >> 7, c = t & 127;
        float acc = bq[c];
        for (int k = 0; k < D_META; ++k) acc += meta[p * D_META + k] * Wq[k * D + c];
        query[t] = acc;
    }
}

// ---------------- final: per-node softmax over metapaths ----------------

__global__ __launch_bounds__(256) void k_final(const float* __restrict__ emb,
                                               const float* __restrict__ query,
                                               float* __restrict__ out) {
    int wv = (blockIdx.x * blockDim.x + threadIdx.x) >> 6;
    int lane = threadIdx.x & 63;
    if (wv >= NREG) return;
    float2 e[4];
    float sc[4];
#pragma unroll
    for (int p = 0; p < 4; ++p) {
        e[p] = *(const float2*)(emb + ((size_t)p * NREG + wv) * D + lane * 2);
        float2 q = *(const float2*)(query + p * D + lane * 2);
        float d = e[p].x * q.x + e[p].y * q.y;
#pragma unroll
        for (int o = 32; o > 0; o >>= 1) d += __shfl_xor(d, o, 64);
        sc[p] = d * SCALE_F;
    }
    float mx = fmaxf(fmaxf(sc[0], sc[1]), fmaxf(sc[2], sc[3]));
    float w[4], sum = 0.f;
#pragma unroll
    for (int p = 0; p < 4; ++p) { w[p] = __expf(sc[p] - mx); sum += w[p]; }
    float inv = 1.f / sum;
    float ox = 0.f, oy = 0.f;
#pragma unroll
    for (int p = 0; p < 4; ++p) { ox += w[p] * inv * e[p].x; oy += w[p] * inv * e[p].y; }
    float2 o; o.x = ox; o.y = oy;
    *(float2*)(out + (size_t)wv * D + lane * 2) = o;
}

// ---------------- launch ----------------

extern "C" void kernel_launch(void* const* d_in, const int* in_sizes, int n_in,
                              void* d_out, int out_size, void* d_ws, size_t ws_size,
                              hipStream_t stream) {
    const float* Etab  = (const float*)d_in[0];
    const float* meta  = (const float*)d_in[1];
    const float* Wroot = (const float*)d_in[2];   // [4][2][128][128]
    const float* Wrel  = (const float*)d_in[3];   // [4][2][128][128]
    const float* bvec  = (const float*)d_in[4];   // [4][2][128]
    const float* Wq    = (const float*)d_in[5];   // [64][128]
    const float* bq    = (const float*)d_in[6];   // [128]
    const int* edge_index = (const int*)d_in[7];  // [4][2][1600000]
    const int* eids       = (const int*)d_in[8];  // [4][100000]
    float* out = (float*)d_out;

    // workspace with lifetime aliasing:
    //   regionA (102.4 MB): pairs (CSR) -> x0 (gather..fused L1) -> emb (fused L2..final)
    char* w = (char*)d_ws;
    char* regionA = w;                           w += (size_t)P_MP * N_NODES * D * 2;     // 102.4 MB
    unsigned short* h1   = (unsigned short*)w;   w += (size_t)P_MP * N_NODES * D * 2;     // 102.4 MB
    int* ssrc = (int*)w;                         w += (size_t)P_MP * N_EDGES * 4;         // 25.6 MB
    int* offs = (int*)w;                         w += (size_t)P_MP * (N_NODES + 1) * 4 + 240;
    int* tbl  = (int*)w;                         w += (size_t)P_MP * P2N * 4;
    int* tblx = (int*)w;                         w += (size_t)P_MP * P2N * 4;
    unsigned short* wswz = (unsigned short*)w;   w += (size_t)16 * D * D * 2;             // 512 KB
    float* query = (float*)w;                    w += 4096;

    uint2* pairs       = (uint2*)regionA;          // CSR phase only
    unsigned short* x0 = (unsigned short*)regionA; // after p4, until fused L1
    float* emb         = (float*)regionA;          // written by fused L2 (x0 dead)

    k_wswz<<<128, 256, 0, stream>>>(Wroot, Wrel, wswz);
    k_query<<<2, 256, 0, stream>>>(meta, Wq, bq, query);

    p1_bhist<<<dim3(CSB, P_MP), 256, 0, stream>>>(edge_index, tbl);
    p2_scan<<<dim3(P_MP), 1024, 0, stream>>>(tbl, tblx, offs);
    p3_coarse<<<dim3(CSB, P_MP), 256, 0, stream>>>(edge_index, tblx, pairs);
    p4_fine<<<dim3(NBKT, P_MP), 256, 0, stream>>>(pairs, tblx, offs, ssrc);

    k_gather<<<dim3(N_NODES * 16 / 256, P_MP), 256, 0, stream>>>(Etab, eids, x0);

    // layer 1: aggregate + dual GEMM fused (M = N_NODES)
    k_fused<true><<<dim3(N_NODES / 16, P_MP), 256, 0, stream>>>(
        x0, offs, ssrc, wswz, bvec, h1, 0, N_NODES);

    // layer 2 (M = NREG; emb overwrites x0 region, x0 dead)
    k_fused<false><<<dim3(NREG / 16, P_MP), 256, 0, stream>>>(
        h1, offs, ssrc, wswz, bvec, emb, 1, NREG);

    k_final<<<(NREG * 64) / 256, 256, 0, stream>>>(emb, query, out);
}